// Round 10
// baseline (127.130 us; speedup 1.0000x reference)
//
#include <hip/hip_runtime.h>

#define NN 256
#define HH 512
#define BB 128
#define EPW 2                  // batch elements interleaved per wave
#define PKS (5 * HH)           // floats per packed step row-set

typedef float f32x4 __attribute__((ext_vector_type(4)));

// ---------------- prep: packed masked/transposed rows, one row-set per step -
// pk[i][0][k] = (k%255 <  i)           ? w2[i][k]     (mu row)
// pk[i][1][k] = (k%255 <  i)           ? w2[256+i][k] (alpha row)
// pk[i][2][k] = (k%255 >= i)           ? w0[k][i]     (w0 column i)
// pk[i][3][k] = (k%255 >= i%255)       ? w1[k][i]     (w1 column i)
// pk[i][4][k] = (k%255 >= (i+255)%255) ? w1[k][i+255]
__global__ __launch_bounds__(512)
void made_prep(const float* __restrict__ w0,
               const float* __restrict__ w1,
               const float* __restrict__ w2,
               float* __restrict__ pk) {
    const int i = blockIdx.x;     // step 0..255
    const int k = threadIdx.x;    // unit 0..511
    const int lev = k % 255;
    float* row = pk + (size_t)i * PKS;
    row[k]          = (lev < i)  ? w2[i * HH + k]        : 0.f;
    row[HH + k]     = (lev < i)  ? w2[(NN + i) * HH + k] : 0.f;
    row[2*HH + k]   = (lev >= i) ? w0[k * NN + i]        : 0.f;
    const int l1 = i % 255;
    row[3*HH + k]   = (lev >= l1) ? w1[k * HH + i]       : 0.f;
    const int j2 = i + 255;
    const int l2 = j2 % 255;
    row[4*HH + k]   = (lev >= l2) ? w1[k * HH + j2]      : 0.f;
}

// ---------------- single-wave sequential kernel -----------------------------
struct B10 { f32x4 q0,q1,q2,q3,q4,q5,q6,q7,q8,q9; };

__device__ __forceinline__ float rl_f(float v, int lane) {
    return __int_as_float(__builtin_amdgcn_readlane(__float_as_int(v), lane));
}

__device__ __forceinline__ f32x4 ld4(const float* p) { return *(const f32x4*)p; }

// pick element s (compile-time after inlining) of the 8 w0 values in q4/q5
__device__ __forceinline__ float q45c(const B10& b, int s) {
    switch (s) {
        case 0: return b.q4[0]; case 1: return b.q4[1];
        case 2: return b.q4[2]; case 3: return b.q4[3];
        case 4: return b.q5[0]; case 5: return b.q5[1];
        case 6: return b.q5[2]; default: return b.q5[3];
    }
}
__device__ __forceinline__ float q67c(const B10& b, int j) {
    return (j < 4) ? b.q6[j] : b.q7[j - 4];
}
__device__ __forceinline__ float q89c(const B10& b, int j) {
    return (j < 4) ? b.q8[j] : b.q9[j - 4];
}

#define DPP_ADD(v, ctrl, rm) \
    ((v) + __int_as_float(__builtin_amdgcn_update_dpp(0, __float_as_int(v), (ctrl), (rm), 0xf, false)))

// Half-split reduce: lanes 0-31 collapse ALL mu partials, lanes 32-63 ALL
// alpha partials (1 shfl + 1 add), then ONE 5-stage DPP reduce serves both:
// lane 31 = sum(mu), lane 63 = sum(alpha).
__device__ __forceinline__ void reduce_half(float pm, float pa, int t,
                                            float& tm, float& ta) {
    float c = (t < 32) ? pm : pa;
    float d = (t < 32) ? pa : pm;
    c += __shfl_xor(d, 32);
    c = DPP_ADD(c, 0x111, 0xf);   // row_shr:1
    c = DPP_ADD(c, 0x112, 0xf);   // row_shr:2
    c = DPP_ADD(c, 0x114, 0xf);   // row_shr:4
    c = DPP_ADD(c, 0x118, 0xf);   // row_shr:8
    c = DPP_ADD(c, 0x142, 0xa);   // row_bcast15 -> rows 1,3
    tm = rl_f(c, 31);
    ta = rl_f(c, 63);
}

#define DOT8(res, A, B)  do {                                   \
    float t01_ = fmaf(h_[1], (A)[1], h_[0] * (A)[0]);           \
    float t23_ = fmaf(h_[3], (A)[3], h_[2] * (A)[2]);           \
    float t45_ = fmaf(h_[5], (B)[1], h_[4] * (B)[0]);           \
    float t67_ = fmaf(h_[7], (B)[3], h_[6] * (B)[2]);           \
    res = (t01_ + t23_) + (t45_ + t67_);                        \
} while (0)

// One autoregressive step for EPW interleaved batch elements (round-9
// verified algebra, per-element). r literal 0..7; BUF = rotating buffer
// (i & 3) loaded 4 steps ago by plain C++ loads. Refill loads pinned at the
// step END by sched_barrier(0); backend emits counted vmcnt at use sites.
#define STEP(g, r, BUF) do {                                                 \
    const int i_  = ((g) << 3) | (r);                                        \
    const int sB_ = ((r) + 7) & 7;                                           \
    const int LB_ = ((r) == 0) ? ((g) + 31) : ((g) + 32);                    \
    const int zl_ = ((g) << 1) + ((r) >> 2);                                 \
    const float w0A_ = rl_f(q45c(BUF, (r)), (g));                            \
    const float w0B_ = rl_f(q45c(BUF, sB_), LB_);                            \
    const float b2m_ = rl_f(b2v[(r)], (g));                                  \
    const float b2a_ = rl_f(b2v[(r)], (g) + 32);                             \
    _Pragma("unroll")                                                        \
    for (int e = 0; e < EPW; ++e) {                                          \
        float h_[8];                                                         \
        _Pragma("unroll")                                                    \
        for (int j = 0; j < 8; ++j) h_[j] = fmaxf(a1v[e][j], 0.f);           \
        float pm_, pa_;                                                      \
        DOT8(pa_, BUF.q2, BUF.q3);                                           \
        DOT8(pm_, BUF.q0, BUF.q1);                                           \
        float tm_, ta_;                                                      \
        reduce_half(pm_, pa_, t, tm_, ta_);                                  \
        float mu_ = tm_ + b2m_;                                              \
        float al_ = ta_ + b2a_;                                              \
        ldacc[e] += al_;                                                     \
        float zi_ = rl_f(zrv[e][(r) & 3], zl_);                              \
        float xi_ = fmaf(zi_, __expf(al_), mu_);                             \
        xo[e][(r) & 3] = (t == zl_) ? xi_ : xo[e][(r) & 3];                  \
        float a0A_ = rl_f(a0v[e][(r)], (g));                                 \
        float a0B_ = rl_f(a0v[e][sB_], LB_);                                 \
        float h0a_ = fmaxf(fmaf(xi_, w0A_, a0A_), 0.f);                      \
        float h0b_ = fmaxf(fmaf(xi_, w0B_, a0B_), 0.f);                      \
        if ((r) < 2 && (g) == 0) {  /* units 510/511 finalize at i=0,1 */    \
            float a0C_ = rl_f(a0v[e][6 + (r)], 63);                          \
            float w0C_ = rl_f(q45c(BUF, 6 + (r)), 63);                       \
            float h0c_ = fmaxf(fmaf(xi_, w0C_, a0C_), 0.f);                  \
            const float* wc_ = ((r) == 0) ? w1c0v : w1c1v;                   \
            _Pragma("unroll")                                                \
            for (int j = 0; j < 8; ++j)                                      \
                a1v[e][j] = fmaf(h0c_, wc_[j], a1v[e][j]);                   \
        }                                                                    \
        _Pragma("unroll")                                                    \
        for (int j = 0; j < 8; ++j)                                          \
            a0v[e][j] = fmaf(xi_, q45c(BUF, j), a0v[e][j]);                  \
        _Pragma("unroll")                                                    \
        for (int j = 0; j < 8; ++j)                                          \
            a1v[e][j] = fmaf(h0b_, q89c(BUF, j),                             \
                             fmaf(h0a_, q67c(BUF, j), a1v[e][j]));           \
    }                                                                        \
    /* ---- refill BUF with step i+4 (plain loads), pinned here ---- */      \
    {                                                                        \
        const float* pf_ = pk + (size_t)((i_ + 4) & 255) * PKS + o8;         \
        BUF.q0 = ld4(pf_);          BUF.q1 = ld4(pf_ + 4);                   \
        BUF.q2 = ld4(pf_ + HH);     BUF.q3 = ld4(pf_ + HH + 4);              \
        BUF.q4 = ld4(pf_ + 2*HH);   BUF.q5 = ld4(pf_ + 2*HH + 4);            \
        BUF.q6 = ld4(pf_ + 3*HH);   BUF.q7 = ld4(pf_ + 3*HH + 4);            \
        BUF.q8 = ld4(pf_ + 4*HH);   BUF.q9 = ld4(pf_ + 4*HH + 4);            \
    }                                                                        \
    __builtin_amdgcn_sched_barrier(0);                                       \
} while (0)

// One 64-thread wave per EPW batch elements. Lane t owns units 8t..8t+7 of
// each element. Distance-4 software pipeline (compiler-managed loads +
// counted waits); sched_barrier(0) per step pins ISSUE order only.
__global__ __launch_bounds__(64, 1)
void made_seq64(const float* __restrict__ z,
                const float* __restrict__ b0g,
                const float* __restrict__ b1g,
                const float* __restrict__ b2g,
                const float* __restrict__ w1,
                const float* __restrict__ pk,
                float* __restrict__ out) {
    const int bb = blockIdx.x;          // element group: elements EPW*bb+e
    const int t  = threadIdx.x;
    const int o8 = t << 3;

    float a0v[EPW][8], a1v[EPW][8], zrv[EPW][4], xo[EPW][4], ldacc[EPW];
    float b2v[8], w1c0v[8], w1c1v[8];
    {
        f32x4 a = ld4(b0g + o8), b = ld4(b0g + o8 + 4);
        f32x4 c = ld4(b1g + o8), d = ld4(b1g + o8 + 4);
        f32x4 e4 = ld4(b2g + o8), f4 = ld4(b2g + o8 + 4);
        #pragma unroll
        for (int e = 0; e < EPW; ++e) {
            #pragma unroll
            for (int j = 0; j < 4; ++j) {
                a0v[e][j] = a[j];  a0v[e][4 + j] = b[j];
                a1v[e][j] = c[j];  a1v[e][4 + j] = d[j];
            }
            f32x4 zz = ld4(z + ((size_t)(EPW * bb + e) << 8) + (t << 2));
            #pragma unroll
            for (int j = 0; j < 4; ++j) { zrv[e][j] = zz[j]; xo[e][j] = 0.f; }
            ldacc[e] = 0.f;
        }
        #pragma unroll
        for (int j = 0; j < 4; ++j) { b2v[j] = e4[j]; b2v[4 + j] = f4[j]; }
    }
    #pragma unroll
    for (int j = 0; j < 8; ++j) {       // w1 rows for units 510, 511
        const int k = o8 + j;
        w1c0v[j] = w1[k * HH + 510];
        w1c1v[j] = ((k % 255) >= 1) ? w1[k * HH + 511] : 0.f;
    }

    // prologue: fill the 4 pipeline buffers (sets 0..3), pin issue position
    B10 Ba, Bb, Bc, Bd;
    {
        const float* p0 = pk + o8;
        Ba.q0 = ld4(p0);        Ba.q1 = ld4(p0 + 4);
        Ba.q2 = ld4(p0 + HH);   Ba.q3 = ld4(p0 + HH + 4);
        Ba.q4 = ld4(p0 + 2*HH); Ba.q5 = ld4(p0 + 2*HH + 4);
        Ba.q6 = ld4(p0 + 3*HH); Ba.q7 = ld4(p0 + 3*HH + 4);
        Ba.q8 = ld4(p0 + 4*HH); Ba.q9 = ld4(p0 + 4*HH + 4);
        const float* p1 = pk + PKS + o8;
        Bb.q0 = ld4(p1);        Bb.q1 = ld4(p1 + 4);
        Bb.q2 = ld4(p1 + HH);   Bb.q3 = ld4(p1 + HH + 4);
        Bb.q4 = ld4(p1 + 2*HH); Bb.q5 = ld4(p1 + 2*HH + 4);
        Bb.q6 = ld4(p1 + 3*HH); Bb.q7 = ld4(p1 + 3*HH + 4);
        Bb.q8 = ld4(p1 + 4*HH); Bb.q9 = ld4(p1 + 4*HH + 4);
        const float* p2 = pk + 2*PKS + o8;
        Bc.q0 = ld4(p2);        Bc.q1 = ld4(p2 + 4);
        Bc.q2 = ld4(p2 + HH);   Bc.q3 = ld4(p2 + HH + 4);
        Bc.q4 = ld4(p2 + 2*HH); Bc.q5 = ld4(p2 + 2*HH + 4);
        Bc.q6 = ld4(p2 + 3*HH); Bc.q7 = ld4(p2 + 3*HH + 4);
        Bc.q8 = ld4(p2 + 4*HH); Bc.q9 = ld4(p2 + 4*HH + 4);
        const float* p3 = pk + 3*PKS + o8;
        Bd.q0 = ld4(p3);        Bd.q1 = ld4(p3 + 4);
        Bd.q2 = ld4(p3 + HH);   Bd.q3 = ld4(p3 + HH + 4);
        Bd.q4 = ld4(p3 + 2*HH); Bd.q5 = ld4(p3 + 2*HH + 4);
        Bd.q6 = ld4(p3 + 3*HH); Bd.q7 = ld4(p3 + 3*HH + 4);
        Bd.q8 = ld4(p3 + 4*HH); Bd.q9 = ld4(p3 + 4*HH + 4);
    }
    __builtin_amdgcn_sched_barrier(0);

    for (int g = 0; g < 32; ++g) {
        STEP(g, 0, Ba); STEP(g, 1, Bb); STEP(g, 2, Bc); STEP(g, 3, Bd);
        STEP(g, 4, Ba); STEP(g, 5, Bb); STEP(g, 6, Bc); STEP(g, 7, Bd);
    }

    #pragma unroll
    for (int e = 0; e < EPW; ++e) {
        *(f32x4*)(out + ((size_t)(EPW * bb + e) << 8) + (t << 2)) =
            (f32x4){xo[e][0], xo[e][1], xo[e][2], xo[e][3]};
        if (t == 0) out[BB * NN + EPW * bb + e] = -ldacc[e];
    }
}

// ---------------- fallback (no workspace): verified round-1 kernel ----------
__global__ __launch_bounds__(256)
void made_seq_fb(const float* __restrict__ z,
                 const float* __restrict__ w0, const float* __restrict__ b0,
                 const float* __restrict__ w1, const float* __restrict__ b1,
                 const float* __restrict__ w2, const float* __restrict__ b2,
                 float* __restrict__ out) {
    const int bb = blockIdx.x;
    const int t  = threadIdx.x;
    const int u0 = t, u1 = t + 256;
    const int l0 = u0 % 255, s0 = u0 / 255;
    const int l1 = u1 % 255, s1 = u1 / 255;
    const int wave = t >> 6, lane = t & 63;

    __shared__ float red[2][4][2];
    __shared__ float pub[2][3][2];

    float a0_0 = b0[u0], a0_1 = b0[u1];
    float a1_0 = b1[u0], a1_1 = b1[u1];
    float ld = 0.f;

    for (int i = 0; i < NN; ++i) {
        float cw2m0 = (l0 < i) ? w2[i * HH + u0] : 0.f;
        float cw2a0 = (l0 < i) ? w2[(NN + i) * HH + u0] : 0.f;
        float cw2m1 = (l1 < i) ? w2[i * HH + u1] : 0.f;
        float cw2a1 = (l1 < i) ? w2[(NN + i) * HH + u1] : 0.f;
        float cw00  = (l0 >= i) ? w0[u0 * NN + i] : 0.f;
        float cw01  = (l1 >= i) ? w0[u1 * NN + i] : 0.f;
        bool g0 = (l0 >= (i % 255)), g1 = (l1 >= (i % 255));
        float w1a0 = g0 ? w1[u0 * HH + i] : 0.f;
        float w1a1 = g1 ? w1[u1 * HH + i] : 0.f;
        float w1b0 = g0 ? w1[u0 * HH + i + 255] : 0.f;
        float w1b1 = g1 ? w1[u1 * HH + i + 255] : 0.f;

        float h10 = fmaxf(a1_0, 0.f), h11 = fmaxf(a1_1, 0.f);
        float pm = h10 * cw2m0 + h11 * cw2m1;
        float pa = h10 * cw2a0 + h11 * cw2a1;
        #pragma unroll
        for (int offs = 32; offs > 0; offs >>= 1) {
            pm += __shfl_xor(pm, offs);
            pa += __shfl_xor(pa, offs);
        }
        const int bf = i & 1;
        if (lane == 0) { red[bf][wave][0] = pm; red[bf][wave][1] = pa; }
        if (l0 == i) { pub[bf][s0][0] = a0_0; pub[bf][s0][1] = cw00; }
        if (l1 == i) { pub[bf][s1][0] = a0_1; pub[bf][s1][1] = cw01; }
        __syncthreads();

        float mu = b2[i]      + red[bf][0][0] + red[bf][1][0] + red[bf][2][0] + red[bf][3][0];
        float al = b2[NN + i] + red[bf][0][1] + red[bf][1][1] + red[bf][2][1] + red[bf][3][1];
        ld += al;
        float xi = fmaf(z[bb * NN + i], __expf(al), mu);
        if (t == 0) out[bb * NN + i] = xi;

        a0_0 = fmaf(xi, cw00, a0_0);
        a0_1 = fmaf(xi, cw01, a0_1);

        float h0a = fmaxf(fmaf(xi, pub[bf][0][1], pub[bf][0][0]), 0.f);
        float h0b = fmaxf(fmaf(xi, pub[bf][1][1], pub[bf][1][0]), 0.f);
        a1_0 = fmaf(h0a, w1a0, a1_0);
        a1_1 = fmaf(h0a, w1a1, a1_1);
        a1_0 = fmaf(h0b, w1b0, a1_0);
        a1_1 = fmaf(h0b, w1b1, a1_1);
        if (i < 2) {
            float w1c0 = (l0 >= i) ? w1[u0 * HH + i + 510] : 0.f;
            float w1c1 = (l1 >= i) ? w1[u1 * HH + i + 510] : 0.f;
            float h0c = fmaxf(fmaf(xi, pub[bf][2][1], pub[bf][2][0]), 0.f);
            a1_0 = fmaf(h0c, w1c0, a1_0);
            a1_1 = fmaf(h0c, w1c1, a1_1);
        }
        __syncthreads();
    }

    if (t == 0) out[BB * NN + bb] = -ld;
}

extern "C" void kernel_launch(void* const* d_in, const int* in_sizes, int n_in,
                              void* d_out, int out_size, void* d_ws, size_t ws_size,
                              hipStream_t stream) {
    const float* z  = (const float*)d_in[0];
    const float* w0 = (const float*)d_in[1];
    const float* b0 = (const float*)d_in[2];
    const float* w1 = (const float*)d_in[3];
    const float* b1 = (const float*)d_in[4];
    const float* w2 = (const float*)d_in[5];
    const float* b2 = (const float*)d_in[6];
    float* out = (float*)d_out;

    const size_t need = (size_t)NN * PKS * sizeof(float);   // 2,621,440 B
    if (ws_size >= need) {
        float* pk = (float*)d_ws;
        made_prep<<<NN, 512, 0, stream>>>(w0, w1, w2, pk);
        made_seq64<<<BB / EPW, 64, 0, stream>>>(z, b0, b1, b2, w1, pk, out);
    } else {
        made_seq_fb<<<BB, 256, 0, stream>>>(z, w0, b0, w1, b1, w2, b2, out);
    }
}